// Round 1
// baseline (774.865 us; speedup 1.0000x reference)
//
#include <hip/hip_runtime.h>

#define N_NODES 100000
#define N_EDGES 1600000
#define NUM_RELS 8
#define KDIM 256      // E_DIM * MAX_LEN
#define HD 64
#define RO 512        // NUM_RELS * 64

__device__ inline unsigned short f2bf(float f) {
    unsigned u = __float_as_uint(f);
    u += 0x7fff + ((u >> 16) & 1);   // round-to-nearest-even
    return (unsigned short)(u >> 16);
}
__device__ inline float bf2f(unsigned short s) {
    return __uint_as_float(((unsigned)s) << 16);
}

// ---------------- weights: Wcat_l[k][r*64+o] = sum_b comp[r,b] V[b,k,o]; smT[k][o] = sm_w[o][k]
__global__ void k_weights(const float* __restrict__ V1, const float* __restrict__ comp1,
                          const float* __restrict__ V2, const float* __restrict__ comp2,
                          const float* __restrict__ sm_w,
                          float* __restrict__ Wcat1, float* __restrict__ Wcat2,
                          float* __restrict__ smT) {
    int idx = blockIdx.x * 256 + threadIdx.x;
    if (idx < 2 * NUM_RELS * 64 * 64) {
        int l = idx >> 15;
        int r = (idx >> 12) & 7;
        int k = (idx >> 6) & 63;
        int o = idx & 63;
        const float* V = l ? V2 : V1;
        const float* comp = l ? comp2 : comp1;
        float s = 0.f;
#pragma unroll
        for (int b = 0; b < 8; b++) s += comp[r * 8 + b] * V[(b * 64 + k) * 64 + o];
        float* W = l ? Wcat2 : Wcat1;
        W[k * RO + r * 64 + o] = s;
    } else {
        int j = idx - 65536;
        if (j < KDIM * HD) {
            int k = j >> 6, o = j & 63;
            smT[k * HD + o] = sm_w[o * KDIM + k];
        }
    }
}

// ---------------- histogram of dst
__global__ void k_hist(const int* __restrict__ dst, int* __restrict__ deg) {
    int e = blockIdx.x * 256 + threadIdx.x;
    if (e < N_EDGES) atomicAdd(&deg[dst[e]], 1);
}

// ---------------- scan (256/block, inclusive per-block + block sums)
__global__ void k_scan1(const int* __restrict__ deg, int* __restrict__ inc, int* __restrict__ bsum) {
    __shared__ int s[256];
    int i = blockIdx.x * 256 + threadIdx.x;
    int v = (i < N_NODES) ? deg[i] : 0;
    s[threadIdx.x] = v;
    __syncthreads();
    for (int off = 1; off < 256; off <<= 1) {
        int t = (threadIdx.x >= off) ? s[threadIdx.x - off] : 0;
        __syncthreads();
        s[threadIdx.x] += t;
        __syncthreads();
    }
    if (i < N_NODES) inc[i] = s[threadIdx.x];
    if (threadIdx.x == 255) bsum[blockIdx.x] = s[255];
}

#define NB_SCAN 391
__global__ void k_scan2(const int* __restrict__ bsum, int* __restrict__ boff) {
    __shared__ int s[512];
    int t = threadIdx.x;
    int v = (t < NB_SCAN) ? bsum[t] : 0;
    s[t] = v;
    __syncthreads();
    for (int off = 1; off < 512; off <<= 1) {
        int u = (t >= off) ? s[t - off] : 0;
        __syncthreads();
        s[t] += u;
        __syncthreads();
    }
    if (t <= NB_SCAN) boff[t] = s[t] - v;   // exclusive; t==NB_SCAN -> total
}

__global__ void k_scan3(const int* __restrict__ inc, const int* __restrict__ deg,
                        const int* __restrict__ boff, int* __restrict__ rowptr) {
    int i = blockIdx.x * 256 + threadIdx.x;
    if (i < N_NODES) rowptr[i] = boff[i >> 8] + inc[i] - deg[i];
    else if (i == N_NODES) rowptr[i] = boff[NB_SCAN];
}

// ---------------- fill CSR: hoff = src*512 + et*64, enorm = norm
__global__ void k_fill(const int* __restrict__ src, const int* __restrict__ dst,
                       const int* __restrict__ et, const float* __restrict__ norm,
                       const int* __restrict__ rowptr, int* __restrict__ cursor,
                       int* __restrict__ hoff, float* __restrict__ enorm) {
    int e = blockIdx.x * 256 + threadIdx.x;
    if (e >= N_EDGES) return;
    int d = dst[e];
    int pos = rowptr[d] + atomicAdd(&cursor[d], 1);
    hoff[pos] = src[e] * RO + et[e] * 64;
    enorm[pos] = norm[e];
}

// ---------------- size matcher: x[n][o] = sum_k emb_w[feat[n][k/32]][k%32] * smT[k][o] + sm_b[o]
// 32 nodes/block; nf staged transposed in LDS (stride 33 -> conflict-free broadcasts)
__launch_bounds__(256)
__global__ void k_sizematch(const int* __restrict__ feat, const float* __restrict__ emb_w,
                            const float* __restrict__ smT, const float* __restrict__ sm_b,
                            float* __restrict__ x) {
    __shared__ float nf2[KDIM * 33];
    int t = threadIdx.x;
    int n0 = blockIdx.x * 32;
    {
        int node = t & 31;
        int slot = t >> 5;           // 0..7
        int gn = n0 + node;
        int fidx = feat[gn * 8 + slot];
        const float4* er = (const float4*)(emb_w + (size_t)fidx * 32);
#pragma unroll
        for (int c4 = 0; c4 < 8; c4++) {
            float4 v = er[c4];
            int kb = slot * 32 + c4 * 4;
            nf2[(kb + 0) * 33 + node] = v.x;
            nf2[(kb + 1) * 33 + node] = v.y;
            nf2[(kb + 2) * 33 + node] = v.z;
            nf2[(kb + 3) * 33 + node] = v.w;
        }
    }
    __syncthreads();
    int to = t & 15;                 // 4 outs each
    int tn = t >> 4;                 // 2 nodes each
    float acc0[4] = {0.f, 0.f, 0.f, 0.f};
    float acc1[4] = {0.f, 0.f, 0.f, 0.f};
    const float4* smT4 = (const float4*)smT;
#pragma unroll 4
    for (int k = 0; k < KDIM; k++) {
        float4 w = smT4[k * 16 + to];
        float a0 = nf2[k * 33 + tn * 2];
        float a1 = nf2[k * 33 + tn * 2 + 1];
        acc0[0] += a0 * w.x; acc0[1] += a0 * w.y; acc0[2] += a0 * w.z; acc0[3] += a0 * w.w;
        acc1[0] += a1 * w.x; acc1[1] += a1 * w.y; acc1[2] += a1 * w.z; acc1[3] += a1 * w.w;
    }
    float4 b = ((const float4*)sm_b)[to];
    int gn0 = n0 + tn * 2;
    float4 r0 = make_float4(acc0[0] + b.x, acc0[1] + b.y, acc0[2] + b.z, acc0[3] + b.w);
    float4 r1 = make_float4(acc1[0] + b.x, acc1[1] + b.y, acc1[2] + b.z, acc1[3] + b.w);
    ((float4*)x)[gn0 * 16 + to] = r0;
    ((float4*)x)[(gn0 + 1) * 16 + to] = r1;
}

// ---------------- transform: H[n][ro] = sum_k xin[n][k] * Wcat[k][ro], bf16 out
// tile: 64 nodes x 128 outs per block; x transposed in LDS; W read via L1 (float4)
__launch_bounds__(256)
__global__ void k_transform(const float* __restrict__ xin, const float* __restrict__ Wcat,
                            unsigned short* __restrict__ H) {
    __shared__ float xT[64 * 68];
    int t = threadIdx.x;
    int n0 = blockIdx.x * 64;
    for (int idx = t; idx < 4096; idx += 256) {
        int r = idx >> 6, c = idx & 63;
        int gn = n0 + r;
        float v = (gn < N_NODES) ? xin[gn * 64 + c] : 0.f;
        xT[c * 68 + r] = v;
    }
    __syncthreads();
    int to = t & 15;                 // outs: ob..ob+3 and ob+64..ob+67
    int tn = t >> 4;                 // nodes: tn*4 .. tn*4+3
    int ob = blockIdx.y * 128 + to * 4;
    float acc[4][8] = {};
    const float4* W4 = (const float4*)Wcat;
#pragma unroll 4
    for (int k = 0; k < 64; k++) {
        float4 a = *(const float4*)&xT[k * 68 + tn * 4];
        float4 w0 = W4[k * 128 + (ob >> 2)];
        float4 w1 = W4[k * 128 + (ob >> 2) + 16];
        float av[4] = {a.x, a.y, a.z, a.w};
#pragma unroll
        for (int i = 0; i < 4; i++) {
            acc[i][0] += av[i] * w0.x; acc[i][1] += av[i] * w0.y;
            acc[i][2] += av[i] * w0.z; acc[i][3] += av[i] * w0.w;
            acc[i][4] += av[i] * w1.x; acc[i][5] += av[i] * w1.y;
            acc[i][6] += av[i] * w1.z; acc[i][7] += av[i] * w1.w;
        }
    }
#pragma unroll
    for (int i = 0; i < 4; i++) {
        int gn = n0 + tn * 4 + i;
        if (gn < N_NODES) {
            ushort4 lo = make_ushort4(f2bf(acc[i][0]), f2bf(acc[i][1]), f2bf(acc[i][2]), f2bf(acc[i][3]));
            ushort4 hi = make_ushort4(f2bf(acc[i][4]), f2bf(acc[i][5]), f2bf(acc[i][6]), f2bf(acc[i][7]));
            *(ushort4*)&H[(size_t)gn * RO + ob] = lo;
            *(ushort4*)&H[(size_t)gn * RO + ob + 64] = hi;
        }
    }
}

// ---------------- aggregate: out[n][lane] = relu?( sum_e norm_e * H[hoff_e + lane] + bias[lane] )
__launch_bounds__(256)
__global__ void k_aggregate(const unsigned short* __restrict__ H, const int* __restrict__ rowptr,
                            const int* __restrict__ hoff, const float* __restrict__ enorm,
                            const float* __restrict__ bias, float* __restrict__ out, int do_relu) {
    int wave = threadIdx.x >> 6;
    int lane = threadIdx.x & 63;
    int node = __builtin_amdgcn_readfirstlane(blockIdx.x * 4 + wave);
    if (node >= N_NODES) return;
    int j0 = rowptr[node];
    int j1 = rowptr[node + 1];
    float y = 0.f;
    int j = j0;
    for (; j + 2 <= j1; j += 2) {
        int oA = hoff[j], oB = hoff[j + 1];
        float nA = enorm[j], nB = enorm[j + 1];
        float fA = bf2f(H[oA + lane]);
        float fB = bf2f(H[oB + lane]);
        y += nA * fA;
        y += nB * fB;
    }
    if (j < j1) {
        y += enorm[j] * bf2f(H[hoff[j] + lane]);
    }
    y += bias[lane];
    if (do_relu) y = fmaxf(y, 0.f);
    out[node * 64 + lane] = y;
}

extern "C" void kernel_launch(void* const* d_in, const int* in_sizes, int n_in,
                              void* d_out, int out_size, void* d_ws, size_t ws_size,
                              hipStream_t stream) {
    const int*   feat  = (const int*)d_in[0];
    const int*   src   = (const int*)d_in[1];
    const int*   dst   = (const int*)d_in[2];
    const int*   etype = (const int*)d_in[3];
    const float* norm  = (const float*)d_in[4];
    const float* emb_w = (const float*)d_in[5];
    const float* sm_w  = (const float*)d_in[6];
    const float* sm_b  = (const float*)d_in[7];
    const float* V1    = (const float*)d_in[8];
    const float* comp1 = (const float*)d_in[9];
    const float* b1    = (const float*)d_in[10];
    const float* V2    = (const float*)d_in[11];
    const float* comp2 = (const float*)d_in[12];
    const float* b2    = (const float*)d_in[13];
    float* out = (float*)d_out;

    // workspace carve (aligned 256B); total ~168 MB
    char* p = (char*)d_ws;
    auto alloc = [&](size_t bytes) { void* q = (void*)p; p += (bytes + 255) & ~(size_t)255; return q; };
    float* x      = (float*)alloc((size_t)N_NODES * 64 * 4);      // 25.6 MB
    float* h      = (float*)alloc((size_t)N_NODES * 64 * 4);      // 25.6 MB
    unsigned short* H = (unsigned short*)alloc((size_t)N_NODES * RO * 2); // 102.4 MB
    float* Wcat1  = (float*)alloc(64 * RO * 4);
    float* Wcat2  = (float*)alloc(64 * RO * 4);
    float* smT    = (float*)alloc(KDIM * HD * 4);
    int*   deg    = (int*)alloc((size_t)N_NODES * 4);
    int*   cursor = (int*)alloc((size_t)N_NODES * 4);
    int*   rowptr = (int*)alloc(((size_t)N_NODES + 1) * 4);
    int*   inc    = (int*)alloc((size_t)N_NODES * 4);
    int*   bsum   = (int*)alloc(512 * 4);
    int*   boff   = (int*)alloc(512 * 4);
    int*   hoff   = (int*)alloc((size_t)N_EDGES * 4);             // 6.4 MB
    float* enorm  = (float*)alloc((size_t)N_EDGES * 4);           // 6.4 MB

    hipMemsetAsync(deg, 0, (size_t)N_NODES * 4, stream);
    hipMemsetAsync(cursor, 0, (size_t)N_NODES * 4, stream);

    k_weights<<<320, 256, 0, stream>>>(V1, comp1, V2, comp2, sm_w, Wcat1, Wcat2, smT);
    k_hist<<<N_EDGES / 256, 256, 0, stream>>>(dst, deg);
    k_scan1<<<NB_SCAN, 256, 0, stream>>>(deg, inc, bsum);
    k_scan2<<<1, 512, 0, stream>>>(bsum, boff);
    k_scan3<<<392, 256, 0, stream>>>(inc, deg, boff, rowptr);
    k_fill<<<N_EDGES / 256, 256, 0, stream>>>(src, dst, etype, norm, rowptr, cursor, hoff, enorm);

    k_sizematch<<<N_NODES / 32, 256, 0, stream>>>(feat, emb_w, smT, sm_b, x);

    k_transform<<<dim3((N_NODES + 63) / 64, 4), 256, 0, stream>>>(x, Wcat1, H);
    k_aggregate<<<N_NODES / 4, 256, 0, stream>>>(H, rowptr, hoff, enorm, b1, h, 1);

    k_transform<<<dim3((N_NODES + 63) / 64, 4), 256, 0, stream>>>(h, Wcat2, H);
    k_aggregate<<<N_NODES / 4, 256, 0, stream>>>(H, rowptr, hoff, enorm, b2, out, 0);
}

// Round 2
// 589.352 us; speedup vs baseline: 1.3148x; 1.3148x over previous
//
#include <hip/hip_runtime.h>

#define N_NODES 100000
#define N_PAD 100032      // padded to 64-node tiles for MFMA transform
#define N_EDGES 1600000
#define NUM_RELS 8
#define KDIM 256      // E_DIM * MAX_LEN
#define HD 64
#define RO 512        // NUM_RELS * 64

typedef __attribute__((ext_vector_type(8))) short bf16x8;
typedef __attribute__((ext_vector_type(4))) float f32x4;

__device__ inline unsigned short f2bf(float f) {
    unsigned u = __float_as_uint(f);
    u += 0x7fff + ((u >> 16) & 1);   // round-to-nearest-even
    return (unsigned short)(u >> 16);
}
__device__ inline float bf2f(unsigned short s) {
    return __uint_as_float(((unsigned)s) << 16);
}

// ---------------- weights:
//  Wpack_l in MFMA B-fragment layout (bf16): Wpack[(((s*4+q)*RO)+ro)*8+j] = W[k=s*32+q*8+j][ro]
//  where W[k][r*64+o] = sum_b comp[r,b] V[b,k,o];  smT[k][o] = sm_w[o][k] (f32)
__global__ void k_weights(const float* __restrict__ V1, const float* __restrict__ comp1,
                          const float* __restrict__ V2, const float* __restrict__ comp2,
                          const float* __restrict__ sm_w,
                          unsigned short* __restrict__ Wpack1, unsigned short* __restrict__ Wpack2,
                          float* __restrict__ smT) {
    int idx = blockIdx.x * 256 + threadIdx.x;
    if (idx < 2 * NUM_RELS * 64 * 64) {
        int l = idx >> 15;
        int r = (idx >> 12) & 7;
        int k = (idx >> 6) & 63;
        int o = idx & 63;
        const float* V = l ? V2 : V1;
        const float* comp = l ? comp2 : comp1;
        float s = 0.f;
#pragma unroll
        for (int b = 0; b < 8; b++) s += comp[r * 8 + b] * V[(b * 64 + k) * 64 + o];
        int ro = r * 64 + o;
        int sstep = k >> 5, q = (k >> 3) & 3, j = k & 7;
        unsigned short* Wp = l ? Wpack2 : Wpack1;
        Wp[(((sstep * 4 + q) * RO) + ro) * 8 + j] = f2bf(s);
    } else {
        int j = idx - 65536;
        if (j < KDIM * HD) {
            int k = j >> 6, o = j & 63;
            smT[k * HD + o] = sm_w[o * KDIM + k];
        }
    }
}

// ---------------- histogram of dst
__global__ void k_hist(const int* __restrict__ dst, int* __restrict__ deg) {
    int e = blockIdx.x * 256 + threadIdx.x;
    if (e < N_EDGES) atomicAdd(&deg[dst[e]], 1);
}

// ---------------- scan
__global__ void k_scan1(const int* __restrict__ deg, int* __restrict__ inc, int* __restrict__ bsum) {
    __shared__ int s[256];
    int i = blockIdx.x * 256 + threadIdx.x;
    int v = (i < N_NODES) ? deg[i] : 0;
    s[threadIdx.x] = v;
    __syncthreads();
    for (int off = 1; off < 256; off <<= 1) {
        int t = (threadIdx.x >= off) ? s[threadIdx.x - off] : 0;
        __syncthreads();
        s[threadIdx.x] += t;
        __syncthreads();
    }
    if (i < N_NODES) inc[i] = s[threadIdx.x];
    if (threadIdx.x == 255) bsum[blockIdx.x] = s[255];
}

#define NB_SCAN 391
__global__ void k_scan2(const int* __restrict__ bsum, int* __restrict__ boff) {
    __shared__ int s[512];
    int t = threadIdx.x;
    int v = (t < NB_SCAN) ? bsum[t] : 0;
    s[t] = v;
    __syncthreads();
    for (int off = 1; off < 512; off <<= 1) {
        int u = (t >= off) ? s[t - off] : 0;
        __syncthreads();
        s[t] += u;
        __syncthreads();
    }
    if (t <= NB_SCAN) boff[t] = s[t] - v;   // exclusive; t==NB_SCAN -> total
}

__global__ void k_scan3(const int* __restrict__ inc, const int* __restrict__ deg,
                        const int* __restrict__ boff, int* __restrict__ rowptr) {
    int i = blockIdx.x * 256 + threadIdx.x;
    if (i < N_NODES) rowptr[i] = boff[i >> 8] + inc[i] - deg[i];
    else if (i == N_NODES) rowptr[i] = boff[NB_SCAN];
}

// ---------------- fill CSR: hoff = src*512 + et*64, enorm = norm
__global__ void k_fill(const int* __restrict__ src, const int* __restrict__ dst,
                       const int* __restrict__ et, const float* __restrict__ norm,
                       const int* __restrict__ rowptr, int* __restrict__ cursor,
                       int* __restrict__ hoff, float* __restrict__ enorm) {
    int e = blockIdx.x * 256 + threadIdx.x;
    if (e >= N_EDGES) return;
    int d = dst[e];
    int pos = rowptr[d] + atomicAdd(&cursor[d], 1);
    hoff[pos] = src[e] * RO + et[e] * 64;
    enorm[pos] = norm[e];
}

// ---------------- size matcher -> bf16 x
__launch_bounds__(256)
__global__ void k_sizematch(const int* __restrict__ feat, const float* __restrict__ emb_w,
                            const float* __restrict__ smT, const float* __restrict__ sm_b,
                            unsigned short* __restrict__ xb) {
    __shared__ float nf2[KDIM * 33];
    int t = threadIdx.x;
    int n0 = blockIdx.x * 32;
    {
        int node = t & 31;
        int slot = t >> 5;           // 0..7
        int gn = n0 + node;
        int fidx = feat[gn * 8 + slot];
        const float4* er = (const float4*)(emb_w + (size_t)fidx * 32);
#pragma unroll
        for (int c4 = 0; c4 < 8; c4++) {
            float4 v = er[c4];
            int kb = slot * 32 + c4 * 4;
            nf2[(kb + 0) * 33 + node] = v.x;
            nf2[(kb + 1) * 33 + node] = v.y;
            nf2[(kb + 2) * 33 + node] = v.z;
            nf2[(kb + 3) * 33 + node] = v.w;
        }
    }
    __syncthreads();
    int to = t & 15;                 // 4 outs each
    int tn = t >> 4;                 // 2 nodes each
    float acc0[4] = {0.f, 0.f, 0.f, 0.f};
    float acc1[4] = {0.f, 0.f, 0.f, 0.f};
    const float4* smT4 = (const float4*)smT;
#pragma unroll 4
    for (int k = 0; k < KDIM; k++) {
        float4 w = smT4[k * 16 + to];
        float a0 = nf2[k * 33 + tn * 2];
        float a1 = nf2[k * 33 + tn * 2 + 1];
        acc0[0] += a0 * w.x; acc0[1] += a0 * w.y; acc0[2] += a0 * w.z; acc0[3] += a0 * w.w;
        acc1[0] += a1 * w.x; acc1[1] += a1 * w.y; acc1[2] += a1 * w.z; acc1[3] += a1 * w.w;
    }
    float4 b = ((const float4*)sm_b)[to];
    int gn0 = n0 + tn * 2;
    ushort4 r0 = make_ushort4(f2bf(acc0[0] + b.x), f2bf(acc0[1] + b.y), f2bf(acc0[2] + b.z), f2bf(acc0[3] + b.w));
    ushort4 r1 = make_ushort4(f2bf(acc1[0] + b.x), f2bf(acc1[1] + b.y), f2bf(acc1[2] + b.z), f2bf(acc1[3] + b.w));
    *(ushort4*)&xb[(size_t)gn0 * 64 + to * 4] = r0;
    *(ushort4*)&xb[((size_t)gn0 + 1) * 64 + to * 4] = r1;
}

// ---------------- transform (MFMA): H[n][ro] = sum_k xb[n][k] * W[k][ro], bf16 out
// block = 4 waves; wave handles 16 nodes x 128 ro; grid = (N_PAD/64, 4). No LDS.
__launch_bounds__(256)
__global__ void k_transform(const unsigned short* __restrict__ xb,
                            const unsigned short* __restrict__ Wp,
                            unsigned short* __restrict__ H) {
    int t = threadIdx.x;
    int wave = t >> 6, lane = t & 63;
    int q = lane >> 4, c = lane & 15;
    int n0 = blockIdx.x * 64 + wave * 16;
    int ro0 = blockIdx.y * 128;
    f32x4 acc[8];
#pragma unroll
    for (int i = 0; i < 8; i++) acc[i] = (f32x4){0.f, 0.f, 0.f, 0.f};
    const bf16x8* X8 = (const bf16x8*)xb;
    const bf16x8* W8 = (const bf16x8*)Wp;
#pragma unroll
    for (int s = 0; s < 2; s++) {
        bf16x8 a = X8[(size_t)(n0 + c) * 8 + s * 4 + q];
#pragma unroll
        for (int tl = 0; tl < 8; tl++) {
            bf16x8 b = W8[(s * 4 + q) * RO + ro0 + tl * 16 + c];
            acc[tl] = __builtin_amdgcn_mfma_f32_16x16x32_bf16(a, b, acc[tl], 0, 0, 0);
        }
    }
    int row_base = n0 + q * 4;
    bool full = (n0 + 15 < N_NODES);
#pragma unroll
    for (int tl = 0; tl < 8; tl++) {
        int col = ro0 + tl * 16 + c;
#pragma unroll
        for (int r = 0; r < 4; r++) {
            int node = row_base + r;
            if (full || node < N_NODES)
                H[(size_t)node * RO + col] = f2bf(acc[tl][r]);
        }
    }
}

// ---------------- aggregate: one wave per node; 2 edges in parallel (lane>>5),
// ushort2 channels per lane (lane&31). mode: 0 = f32 out, 1 = relu + bf16 out
__launch_bounds__(256)
__global__ void k_aggregate(const unsigned short* __restrict__ H, const int* __restrict__ rowptr,
                            const int* __restrict__ hoff, const float* __restrict__ enorm,
                            const float* __restrict__ bias, float* __restrict__ outf,
                            unsigned short* __restrict__ outb, int mode) {
    int wave = threadIdx.x >> 6;
    int lane = threadIdx.x & 63;
    int node = blockIdx.x * 4 + wave;
    if (node >= N_NODES) return;
    int j0 = rowptr[node];
    int j1 = rowptr[node + 1];
    int es = lane >> 5;
    int c2 = (lane & 31) * 2;
    float ax = 0.f, ay = 0.f;
    int j = j0 + es;
    for (; j + 2 < j1; j += 4) {
        int oA = hoff[j];
        float nA = enorm[j];
        unsigned vA = *(const unsigned*)(H + oA + c2);
        int oB = hoff[j + 2];
        float nB = enorm[j + 2];
        unsigned vB = *(const unsigned*)(H + oB + c2);
        ax += nA * bf2f((unsigned short)vA);
        ay += nA * bf2f((unsigned short)(vA >> 16));
        ax += nB * bf2f((unsigned short)vB);
        ay += nB * bf2f((unsigned short)(vB >> 16));
    }
    for (; j < j1; j += 2) {
        int o = hoff[j];
        float nn = enorm[j];
        unsigned v = *(const unsigned*)(H + o + c2);
        ax += nn * bf2f((unsigned short)v);
        ay += nn * bf2f((unsigned short)(v >> 16));
    }
    ax += __shfl_xor(ax, 32);
    ay += __shfl_xor(ay, 32);
    if (es == 0) {
        float2 b = *(const float2*)(bias + c2);
        float rx = ax + b.x, ry = ay + b.y;
        if (mode == 1) {
            rx = fmaxf(rx, 0.f); ry = fmaxf(ry, 0.f);
            ushort2 pk = make_ushort2(f2bf(rx), f2bf(ry));
            *(ushort2*)&outb[(size_t)node * 64 + c2] = pk;
        } else {
            *(float2*)&outf[(size_t)node * 64 + c2] = make_float2(rx, ry);
        }
    }
}

extern "C" void kernel_launch(void* const* d_in, const int* in_sizes, int n_in,
                              void* d_out, int out_size, void* d_ws, size_t ws_size,
                              hipStream_t stream) {
    const int*   feat  = (const int*)d_in[0];
    const int*   src   = (const int*)d_in[1];
    const int*   dst   = (const int*)d_in[2];
    const int*   etype = (const int*)d_in[3];
    const float* norm  = (const float*)d_in[4];
    const float* emb_w = (const float*)d_in[5];
    const float* sm_w  = (const float*)d_in[6];
    const float* sm_b  = (const float*)d_in[7];
    const float* V1    = (const float*)d_in[8];
    const float* comp1 = (const float*)d_in[9];
    const float* b1    = (const float*)d_in[10];
    const float* V2    = (const float*)d_in[11];
    const float* comp2 = (const float*)d_in[12];
    const float* b2    = (const float*)d_in[13];
    float* out = (float*)d_out;

    char* p = (char*)d_ws;
    auto alloc = [&](size_t bytes) { void* q = (void*)p; p += (bytes + 255) & ~(size_t)255; return q; };
    unsigned short* xb = (unsigned short*)alloc((size_t)N_PAD * 64 * 2);   // 12.8 MB
    unsigned short* hb = (unsigned short*)alloc((size_t)N_PAD * 64 * 2);   // 12.8 MB
    unsigned short* H  = (unsigned short*)alloc((size_t)N_NODES * RO * 2); // 102.4 MB
    unsigned short* Wpack1 = (unsigned short*)alloc(64 * RO * 2);
    unsigned short* Wpack2 = (unsigned short*)alloc(64 * RO * 2);
    float* smT    = (float*)alloc(KDIM * HD * 4);
    int*   deg    = (int*)alloc((size_t)N_NODES * 4);
    int*   cursor = (int*)alloc((size_t)N_NODES * 4);
    int*   rowptr = (int*)alloc(((size_t)N_NODES + 1) * 4);
    int*   inc    = (int*)alloc((size_t)N_NODES * 4);
    int*   bsum   = (int*)alloc(512 * 4);
    int*   boff   = (int*)alloc(512 * 4);
    int*   hoff   = (int*)alloc((size_t)N_EDGES * 4);
    float* enorm  = (float*)alloc((size_t)N_EDGES * 4);

    hipMemsetAsync(deg, 0, (size_t)N_NODES * 4, stream);
    hipMemsetAsync(cursor, 0, (size_t)N_NODES * 4, stream);

    k_weights<<<320, 256, 0, stream>>>(V1, comp1, V2, comp2, sm_w, Wpack1, Wpack2, smT);
    k_hist<<<N_EDGES / 256, 256, 0, stream>>>(dst, deg);
    k_scan1<<<NB_SCAN, 256, 0, stream>>>(deg, inc, bsum);
    k_scan2<<<1, 512, 0, stream>>>(bsum, boff);
    k_scan3<<<392, 256, 0, stream>>>(inc, deg, boff, rowptr);
    k_fill<<<N_EDGES / 256, 256, 0, stream>>>(src, dst, etype, norm, rowptr, cursor, hoff, enorm);

    k_sizematch<<<N_NODES / 32, 256, 0, stream>>>(feat, emb_w, smT, sm_b, xb);

    k_transform<<<dim3(N_PAD / 64, 4), 256, 0, stream>>>(xb, Wpack1, H);
    k_aggregate<<<N_NODES / 4, 256, 0, stream>>>(H, rowptr, hoff, enorm, b1, nullptr, hb, 1);

    k_transform<<<dim3(N_PAD / 64, 4), 256, 0, stream>>>(hb, Wpack2, H);
    k_aggregate<<<N_NODES / 4, 256, 0, stream>>>(H, rowptr, hoff, enorm, b2, out, nullptr, 0);
}

// Round 3
// 507.621 us; speedup vs baseline: 1.5265x; 1.1610x over previous
//
#include <hip/hip_runtime.h>

#define N_NODES 100000
#define N_PAD 100032      // padded to 64-node tiles for MFMA
#define N_EDGES 1600000
#define NUM_RELS 8
#define KDIM 256      // E_DIM * MAX_LEN
#define HD 64
#define RO 512        // NUM_RELS * 64

typedef __attribute__((ext_vector_type(8))) short bf16x8;
typedef __attribute__((ext_vector_type(4))) float f32x4;

__device__ inline unsigned short f2bf(float f) {
    unsigned u = __float_as_uint(f);
    u += 0x7fff + ((u >> 16) & 1);   // round-to-nearest-even
    return (unsigned short)(u >> 16);
}
__device__ inline float bf2f(unsigned short s) {
    return __uint_as_float(((unsigned)s) << 16);
}
// truncating pack of two f32 -> two bf16 in one u32 (compiler emits v_perm)
__device__ inline unsigned packtrunc(float x, float y) {
    return (__float_as_uint(x) >> 16) | (__float_as_uint(y) & 0xffff0000u);
}

// ---------------- weights:
//  Wpack_l in MFMA B-fragment layout (bf16): Wpack[(((s*4+q)*RO)+ro)*8+j] = W[k=s*32+q*8+j][ro]
//  where W[k][r*64+o] = sum_b comp[r,b] V[b,k,o]
//  smPack in B-fragment layout for the size matcher: smPack[((s*4+q)*64+o)*8+j] = sm_w[o][s*32+q*8+j]
__global__ void k_weights(const float* __restrict__ V1, const float* __restrict__ comp1,
                          const float* __restrict__ V2, const float* __restrict__ comp2,
                          const float* __restrict__ sm_w,
                          unsigned short* __restrict__ Wpack1, unsigned short* __restrict__ Wpack2,
                          unsigned short* __restrict__ smPack) {
    int idx = blockIdx.x * 256 + threadIdx.x;
    if (idx < 2 * NUM_RELS * 64 * 64) {
        int l = idx >> 15;
        int r = (idx >> 12) & 7;
        int k = (idx >> 6) & 63;
        int o = idx & 63;
        const float* V = l ? V2 : V1;
        const float* comp = l ? comp2 : comp1;
        float s = 0.f;
#pragma unroll
        for (int b = 0; b < 8; b++) s += comp[r * 8 + b] * V[(b * 64 + k) * 64 + o];
        int ro = r * 64 + o;
        int sstep = k >> 5, q = (k >> 3) & 3, j = k & 7;
        unsigned short* Wp = l ? Wpack2 : Wpack1;
        Wp[(((sstep * 4 + q) * RO) + ro) * 8 + j] = f2bf(s);
    } else {
        int j = idx - 65536;
        if (j < KDIM * HD) {
            int k = j >> 6, o = j & 63;
            int s = k >> 5, q = (k >> 3) & 3, jj = k & 7;
            smPack[(((s * 4 + q) * 64) + o) * 8 + jj] = f2bf(sm_w[o * KDIM + k]);
        }
    }
}

// ---------------- histogram of dst
__global__ void k_hist(const int* __restrict__ dst, int* __restrict__ deg) {
    int e = blockIdx.x * 256 + threadIdx.x;
    if (e < N_EDGES) atomicAdd(&deg[dst[e]], 1);
}

// ---------------- scan
__global__ void k_scan1(const int* __restrict__ deg, int* __restrict__ inc, int* __restrict__ bsum) {
    __shared__ int s[256];
    int i = blockIdx.x * 256 + threadIdx.x;
    int v = (i < N_NODES) ? deg[i] : 0;
    s[threadIdx.x] = v;
    __syncthreads();
    for (int off = 1; off < 256; off <<= 1) {
        int t = (threadIdx.x >= off) ? s[threadIdx.x - off] : 0;
        __syncthreads();
        s[threadIdx.x] += t;
        __syncthreads();
    }
    if (i < N_NODES) inc[i] = s[threadIdx.x];
    if (threadIdx.x == 255) bsum[blockIdx.x] = s[255];
}

#define NB_SCAN 391
__global__ void k_scan2(const int* __restrict__ bsum, int* __restrict__ boff) {
    __shared__ int s[512];
    int t = threadIdx.x;
    int v = (t < NB_SCAN) ? bsum[t] : 0;
    s[t] = v;
    __syncthreads();
    for (int off = 1; off < 512; off <<= 1) {
        int u = (t >= off) ? s[t - off] : 0;
        __syncthreads();
        s[t] += u;
        __syncthreads();
    }
    if (t <= NB_SCAN) boff[t] = s[t] - v;   // exclusive; t==NB_SCAN -> total
}

__global__ void k_scan3(const int* __restrict__ inc, const int* __restrict__ deg,
                        const int* __restrict__ boff, int* __restrict__ rowptr) {
    int i = blockIdx.x * 256 + threadIdx.x;
    if (i < N_NODES) rowptr[i] = boff[i >> 8] + inc[i] - deg[i];
    else if (i == N_NODES) rowptr[i] = boff[NB_SCAN];
}

// ---------------- fill CSR: hoff = src*512 + et*64, enorm = norm
__global__ void k_fill(const int* __restrict__ src, const int* __restrict__ dst,
                       const int* __restrict__ et, const float* __restrict__ norm,
                       const int* __restrict__ rowptr, int* __restrict__ cursor,
                       int* __restrict__ hoff, float* __restrict__ enorm) {
    int e = blockIdx.x * 256 + threadIdx.x;
    if (e >= N_EDGES) return;
    int d = dst[e];
    int pos = rowptr[d] + atomicAdd(&cursor[d], 1);
    hoff[pos] = src[e] * RO + et[e] * 64;
    enorm[pos] = norm[e];
}

// ---------------- size matcher (MFMA, no LDS): x[n][o] = sum_k nf[n][k] sm_w[o][k] + sm_b[o]
// A-fragment = 32B slice of the gathered emb row itself (k-spans stay inside one emb row).
// wave: 16 nodes x 64 outs; block 4 waves; grid N_PAD/64.
__launch_bounds__(256)
__global__ void k_sizematch(const int* __restrict__ feat, const float* __restrict__ emb_w,
                            const unsigned short* __restrict__ smPack, const float* __restrict__ sm_b,
                            unsigned short* __restrict__ xb) {
    int t = threadIdx.x;
    int wave = t >> 6, lane = t & 63;
    int q = lane >> 4, c = lane & 15;
    int n0 = blockIdx.x * 64 + wave * 16;
    int node = n0 + c;
    int nclamp = (node < N_NODES) ? node : (N_NODES - 1);
    const int4* fr = (const int4*)(feat + (size_t)nclamp * 8);
    int4 f0 = fr[0], f1 = fr[1];
    int fidx[8] = {f0.x, f0.y, f0.z, f0.w, f1.x, f1.y, f1.z, f1.w};
    f32x4 acc[4];
#pragma unroll
    for (int i = 0; i < 4; i++) acc[i] = (f32x4){0.f, 0.f, 0.f, 0.f};
    const bf16x8* B8 = (const bf16x8*)smPack;
#pragma unroll
    for (int s = 0; s < 8; s++) {
        const float4* ar = (const float4*)(emb_w + (size_t)fidx[s] * 32 + q * 8);
        float4 a0 = ar[0], a1 = ar[1];
        union { unsigned u[4]; bf16x8 v; } A;
        A.u[0] = packtrunc(a0.x, a0.y);
        A.u[1] = packtrunc(a0.z, a0.w);
        A.u[2] = packtrunc(a1.x, a1.y);
        A.u[3] = packtrunc(a1.z, a1.w);
#pragma unroll
        for (int tl = 0; tl < 4; tl++) {
            bf16x8 b = B8[(s * 4 + q) * 64 + tl * 16 + c];
            acc[tl] = __builtin_amdgcn_mfma_f32_16x16x32_bf16(A.v, b, acc[tl], 0, 0, 0);
        }
    }
    int row_base = n0 + q * 4;
    bool full = (n0 + 15 < N_NODES);
#pragma unroll
    for (int tl = 0; tl < 4; tl++) {
        int o = tl * 16 + c;
        float bia = sm_b[o];
#pragma unroll
        for (int r = 0; r < 4; r++) {
            int nd = row_base + r;
            if (full || nd < N_NODES)
                xb[(size_t)nd * 64 + o] = f2bf(acc[tl][r] + bia);
        }
    }
}

// ---------------- transform (MFMA): H[n][ro] = sum_k xb[n][k] * W[k][ro], bf16 out
// block = 4 waves; wave handles 16 nodes x 128 ro; grid = (N_PAD/64, 4). No LDS.
__launch_bounds__(256)
__global__ void k_transform(const unsigned short* __restrict__ xb,
                            const unsigned short* __restrict__ Wp,
                            unsigned short* __restrict__ H) {
    int t = threadIdx.x;
    int wave = t >> 6, lane = t & 63;
    int q = lane >> 4, c = lane & 15;
    int n0 = blockIdx.x * 64 + wave * 16;
    int ro0 = blockIdx.y * 128;
    f32x4 acc[8];
#pragma unroll
    for (int i = 0; i < 8; i++) acc[i] = (f32x4){0.f, 0.f, 0.f, 0.f};
    const bf16x8* X8 = (const bf16x8*)xb;
    const bf16x8* W8 = (const bf16x8*)Wp;
#pragma unroll
    for (int s = 0; s < 2; s++) {
        bf16x8 a = X8[(size_t)(n0 + c) * 8 + s * 4 + q];
#pragma unroll
        for (int tl = 0; tl < 8; tl++) {
            bf16x8 b = W8[(s * 4 + q) * RO + ro0 + tl * 16 + c];
            acc[tl] = __builtin_amdgcn_mfma_f32_16x16x32_bf16(a, b, acc[tl], 0, 0, 0);
        }
    }
    int row_base = n0 + q * 4;
    bool full = (n0 + 15 < N_NODES);
#pragma unroll
    for (int tl = 0; tl < 8; tl++) {
        int col = ro0 + tl * 16 + c;
#pragma unroll
        for (int r = 0; r < 4; r++) {
            int node = row_base + r;
            if (full || node < N_NODES)
                H[(size_t)node * RO + col] = f2bf(acc[tl][r]);
        }
    }
}

// ---------------- aggregate: one wave per node; 4 edges in flight (lane>>4),
// ushort4 channels per lane (lane&15). mode: 0 = f32 out, 1 = relu + bf16 out
__launch_bounds__(256)
__global__ void k_aggregate(const unsigned short* __restrict__ H, const int* __restrict__ rowptr,
                            const int* __restrict__ hoff, const float* __restrict__ enorm,
                            const float* __restrict__ bias, float* __restrict__ outf,
                            unsigned short* __restrict__ outb, int mode) {
    int wave = threadIdx.x >> 6;
    int lane = threadIdx.x & 63;
    int node = blockIdx.x * 4 + wave;
    if (node >= N_NODES) return;
    int j0 = rowptr[node];
    int j1 = rowptr[node + 1];
    int es = lane >> 4;          // edge slot 0..3
    int c4 = (lane & 15) * 4;    // channel base
    float a0 = 0.f, a1 = 0.f, a2 = 0.f, a3 = 0.f;
    for (int j = j0 + es; j < j1; j += 4) {
        int o = hoff[j];
        float nn = enorm[j];
        ushort4 v = *(const ushort4*)(H + o + c4);
        a0 += nn * bf2f(v.x);
        a1 += nn * bf2f(v.y);
        a2 += nn * bf2f(v.z);
        a3 += nn * bf2f(v.w);
    }
    a0 += __shfl_xor(a0, 16); a1 += __shfl_xor(a1, 16);
    a2 += __shfl_xor(a2, 16); a3 += __shfl_xor(a3, 16);
    a0 += __shfl_xor(a0, 32); a1 += __shfl_xor(a1, 32);
    a2 += __shfl_xor(a2, 32); a3 += __shfl_xor(a3, 32);
    if (es == 0) {
        float4 b = *(const float4*)(bias + c4);
        float r0 = a0 + b.x, r1 = a1 + b.y, r2 = a2 + b.z, r3 = a3 + b.w;
        if (mode == 1) {
            r0 = fmaxf(r0, 0.f); r1 = fmaxf(r1, 0.f);
            r2 = fmaxf(r2, 0.f); r3 = fmaxf(r3, 0.f);
            ushort4 pk = make_ushort4(f2bf(r0), f2bf(r1), f2bf(r2), f2bf(r3));
            *(ushort4*)&outb[(size_t)node * 64 + c4] = pk;
        } else {
            *(float4*)&outf[(size_t)node * 64 + c4] = make_float4(r0, r1, r2, r3);
        }
    }
}

extern "C" void kernel_launch(void* const* d_in, const int* in_sizes, int n_in,
                              void* d_out, int out_size, void* d_ws, size_t ws_size,
                              hipStream_t stream) {
    const int*   feat  = (const int*)d_in[0];
    const int*   src   = (const int*)d_in[1];
    const int*   dst   = (const int*)d_in[2];
    const int*   etype = (const int*)d_in[3];
    const float* norm  = (const float*)d_in[4];
    const float* emb_w = (const float*)d_in[5];
    const float* sm_w  = (const float*)d_in[6];
    const float* sm_b  = (const float*)d_in[7];
    const float* V1    = (const float*)d_in[8];
    const float* comp1 = (const float*)d_in[9];
    const float* b1    = (const float*)d_in[10];
    const float* V2    = (const float*)d_in[11];
    const float* comp2 = (const float*)d_in[12];
    const float* b2    = (const float*)d_in[13];
    float* out = (float*)d_out;

    char* p = (char*)d_ws;
    auto alloc = [&](size_t bytes) { void* q = (void*)p; p += (bytes + 255) & ~(size_t)255; return q; };
    unsigned short* xb = (unsigned short*)alloc((size_t)N_PAD * 64 * 2);   // 12.8 MB
    unsigned short* hb = (unsigned short*)alloc((size_t)N_PAD * 64 * 2);   // 12.8 MB
    unsigned short* H  = (unsigned short*)alloc((size_t)N_NODES * RO * 2); // 102.4 MB
    unsigned short* Wpack1 = (unsigned short*)alloc(64 * RO * 2);
    unsigned short* Wpack2 = (unsigned short*)alloc(64 * RO * 2);
    unsigned short* smPack = (unsigned short*)alloc(KDIM * HD * 2);        // 32 KB
    int*   deg    = (int*)alloc((size_t)N_NODES * 4);
    int*   cursor = (int*)alloc((size_t)N_NODES * 4);
    int*   rowptr = (int*)alloc(((size_t)N_NODES + 1) * 4);
    int*   inc    = (int*)alloc((size_t)N_NODES * 4);
    int*   bsum   = (int*)alloc(512 * 4);
    int*   boff   = (int*)alloc(512 * 4);
    int*   hoff   = (int*)alloc((size_t)N_EDGES * 4);
    float* enorm  = (float*)alloc((size_t)N_EDGES * 4);

    hipMemsetAsync(deg, 0, (size_t)N_NODES * 4, stream);
    hipMemsetAsync(cursor, 0, (size_t)N_NODES * 4, stream);

    k_weights<<<320, 256, 0, stream>>>(V1, comp1, V2, comp2, sm_w, Wpack1, Wpack2, smPack);
    k_hist<<<N_EDGES / 256, 256, 0, stream>>>(dst, deg);
    k_scan1<<<NB_SCAN, 256, 0, stream>>>(deg, inc, bsum);
    k_scan2<<<1, 512, 0, stream>>>(bsum, boff);
    k_scan3<<<392, 256, 0, stream>>>(inc, deg, boff, rowptr);
    k_fill<<<N_EDGES / 256, 256, 0, stream>>>(src, dst, etype, norm, rowptr, cursor, hoff, enorm);

    k_sizematch<<<N_PAD / 64, 256, 0, stream>>>(feat, emb_w, smPack, sm_b, xb);

    k_transform<<<dim3(N_PAD / 64, 4), 256, 0, stream>>>(xb, Wpack1, H);
    k_aggregate<<<N_NODES / 4, 256, 0, stream>>>(H, rowptr, hoff, enorm, b1, nullptr, hb, 1);

    k_transform<<<dim3(N_PAD / 64, 4), 256, 0, stream>>>(hb, Wpack2, H);
    k_aggregate<<<N_NODES / 4, 256, 0, stream>>>(H, rowptr, hoff, enorm, b2, out, nullptr, 0);
}

// Round 4
// 435.792 us; speedup vs baseline: 1.7781x; 1.1648x over previous
//
#include <hip/hip_runtime.h>

#define N_NODES 100000
#define N_PAD 100032      // padded to 64-node tiles for MFMA
#define N_EDGES 1600000
#define NUM_RELS 8
#define KDIM 256      // E_DIM * MAX_LEN
#define HD 64
#define RO 512        // NUM_RELS * 64

typedef __attribute__((ext_vector_type(8))) short bf16x8;
typedef __attribute__((ext_vector_type(4))) float f32x4;

__device__ inline unsigned short f2bf(float f) {
    unsigned u = __float_as_uint(f);
    u += 0x7fff + ((u >> 16) & 1);   // round-to-nearest-even
    return (unsigned short)(u >> 16);
}
__device__ inline float bf2f(unsigned short s) {
    return __uint_as_float(((unsigned)s) << 16);
}
// truncating pack of two f32 -> two bf16 in one u32 (compiler emits v_perm)
__device__ inline unsigned packtrunc(float x, float y) {
    return (__float_as_uint(x) >> 16) | (__float_as_uint(y) & 0xffff0000u);
}

// ---------------- weights:
//  Wpack_l in MFMA B-fragment layout (bf16): Wpack[(((s*4+q)*RO)+ro)*8+j] = W[k=s*32+q*8+j][ro]
//  where W[k][r*64+o] = sum_b comp[r,b] V[b,k,o]
//  smPack in B-fragment layout for the size matcher: smPack[((s*4+q)*64+o)*8+j] = sm_w[o][s*32+q*8+j]
__global__ void k_weights(const float* __restrict__ V1, const float* __restrict__ comp1,
                          const float* __restrict__ V2, const float* __restrict__ comp2,
                          const float* __restrict__ sm_w,
                          unsigned short* __restrict__ Wpack1, unsigned short* __restrict__ Wpack2,
                          unsigned short* __restrict__ smPack) {
    int idx = blockIdx.x * 256 + threadIdx.x;
    if (idx < 2 * NUM_RELS * 64 * 64) {
        int l = idx >> 15;
        int r = (idx >> 12) & 7;
        int k = (idx >> 6) & 63;
        int o = idx & 63;
        const float* V = l ? V2 : V1;
        const float* comp = l ? comp2 : comp1;
        float s = 0.f;
#pragma unroll
        for (int b = 0; b < 8; b++) s += comp[r * 8 + b] * V[(b * 64 + k) * 64 + o];
        int ro = r * 64 + o;
        int sstep = k >> 5, q = (k >> 3) & 3, j = k & 7;
        unsigned short* Wp = l ? Wpack2 : Wpack1;
        Wp[(((sstep * 4 + q) * RO) + ro) * 8 + j] = f2bf(s);
    } else {
        int j = idx - 65536;
        if (j < KDIM * HD) {
            int k = j >> 6, o = j & 63;
            int s = k >> 5, q = (k >> 3) & 3, jj = k & 7;
            smPack[(((s * 4 + q) * 64) + o) * 8 + jj] = f2bf(sm_w[o * KDIM + k]);
        }
    }
}

// ---------------- histogram of dst; atomic return value IS the CSR ticket
__global__ void k_hist(const int* __restrict__ dst, int* __restrict__ deg, int* __restrict__ ticket) {
    int e = blockIdx.x * 256 + threadIdx.x;
    if (e < N_EDGES) ticket[e] = atomicAdd(&deg[dst[e]], 1);
}

// ---------------- scan
__global__ void k_scan1(const int* __restrict__ deg, int* __restrict__ inc, int* __restrict__ bsum) {
    __shared__ int s[256];
    int i = blockIdx.x * 256 + threadIdx.x;
    int v = (i < N_NODES) ? deg[i] : 0;
    s[threadIdx.x] = v;
    __syncthreads();
    for (int off = 1; off < 256; off <<= 1) {
        int t = (threadIdx.x >= off) ? s[threadIdx.x - off] : 0;
        __syncthreads();
        s[threadIdx.x] += t;
        __syncthreads();
    }
    if (i < N_NODES) inc[i] = s[threadIdx.x];
    if (threadIdx.x == 255) bsum[blockIdx.x] = s[255];
}

#define NB_SCAN 391
__global__ void k_scan2(const int* __restrict__ bsum, int* __restrict__ boff) {
    __shared__ int s[512];
    int t = threadIdx.x;
    int v = (t < NB_SCAN) ? bsum[t] : 0;
    s[t] = v;
    __syncthreads();
    for (int off = 1; off < 512; off <<= 1) {
        int u = (t >= off) ? s[t - off] : 0;
        __syncthreads();
        s[t] += u;
        __syncthreads();
    }
    if (t <= NB_SCAN) boff[t] = s[t] - v;   // exclusive; t==NB_SCAN -> total
}

__global__ void k_scan3(const int* __restrict__ inc, const int* __restrict__ deg,
                        const int* __restrict__ boff, int* __restrict__ rowptr) {
    int i = blockIdx.x * 256 + threadIdx.x;
    if (i < N_NODES) rowptr[i] = boff[i >> 8] + inc[i] - deg[i];
    else if (i == N_NODES) rowptr[i] = boff[NB_SCAN];
}

// ---------------- fill CSR (no atomics): edata[pos] = {src*512+et*64, norm_bits}
__global__ void k_fill(const int* __restrict__ src, const int* __restrict__ dst,
                       const int* __restrict__ et, const float* __restrict__ norm,
                       const int* __restrict__ rowptr, const int* __restrict__ ticket,
                       int2* __restrict__ edata) {
    int e = blockIdx.x * 256 + threadIdx.x;
    if (e >= N_EDGES) return;
    int d = dst[e];
    int pos = rowptr[d] + ticket[e];
    edata[pos] = make_int2(src[e] * RO + et[e] * 64, __float_as_int(norm[e]));
}

// ---------------- size matcher (MFMA, no LDS): x[n][o] = sum_k nf[n][k] sm_w[o][k] + sm_b[o]
__launch_bounds__(256)
__global__ void k_sizematch(const int* __restrict__ feat, const float* __restrict__ emb_w,
                            const unsigned short* __restrict__ smPack, const float* __restrict__ sm_b,
                            unsigned short* __restrict__ xb) {
    int t = threadIdx.x;
    int wave = t >> 6, lane = t & 63;
    int q = lane >> 4, c = lane & 15;
    int n0 = blockIdx.x * 64 + wave * 16;
    int node = n0 + c;
    int nclamp = (node < N_NODES) ? node : (N_NODES - 1);
    const int4* fr = (const int4*)(feat + (size_t)nclamp * 8);
    int4 f0 = fr[0], f1 = fr[1];
    int fidx[8] = {f0.x, f0.y, f0.z, f0.w, f1.x, f1.y, f1.z, f1.w};
    f32x4 acc[4];
#pragma unroll
    for (int i = 0; i < 4; i++) acc[i] = (f32x4){0.f, 0.f, 0.f, 0.f};
    const bf16x8* B8 = (const bf16x8*)smPack;
#pragma unroll
    for (int s = 0; s < 8; s++) {
        const float4* ar = (const float4*)(emb_w + (size_t)fidx[s] * 32 + q * 8);
        float4 a0 = ar[0], a1 = ar[1];
        union { unsigned u[4]; bf16x8 v; } A;
        A.u[0] = packtrunc(a0.x, a0.y);
        A.u[1] = packtrunc(a0.z, a0.w);
        A.u[2] = packtrunc(a1.x, a1.y);
        A.u[3] = packtrunc(a1.z, a1.w);
#pragma unroll
        for (int tl = 0; tl < 4; tl++) {
            bf16x8 b = B8[(s * 4 + q) * 64 + tl * 16 + c];
            acc[tl] = __builtin_amdgcn_mfma_f32_16x16x32_bf16(A.v, b, acc[tl], 0, 0, 0);
        }
    }
    int row_base = n0 + q * 4;
    bool full = (n0 + 15 < N_NODES);
#pragma unroll
    for (int tl = 0; tl < 4; tl++) {
        int o = tl * 16 + c;
        float bia = sm_b[o];
#pragma unroll
        for (int r = 0; r < 4; r++) {
            int nd = row_base + r;
            if (full || nd < N_NODES)
                xb[(size_t)nd * 64 + o] = f2bf(acc[tl][r] + bia);
        }
    }
}

// ---------------- transform (MFMA): H[n][ro] = sum_k xb[n][k] * W[k][ro], bf16 out
__launch_bounds__(256)
__global__ void k_transform(const unsigned short* __restrict__ xb,
                            const unsigned short* __restrict__ Wp,
                            unsigned short* __restrict__ H) {
    int t = threadIdx.x;
    int wave = t >> 6, lane = t & 63;
    int q = lane >> 4, c = lane & 15;
    int n0 = blockIdx.x * 64 + wave * 16;
    int ro0 = blockIdx.y * 128;
    f32x4 acc[8];
#pragma unroll
    for (int i = 0; i < 8; i++) acc[i] = (f32x4){0.f, 0.f, 0.f, 0.f};
    const bf16x8* X8 = (const bf16x8*)xb;
    const bf16x8* W8 = (const bf16x8*)Wp;
#pragma unroll
    for (int s = 0; s < 2; s++) {
        bf16x8 a = X8[(size_t)(n0 + c) * 8 + s * 4 + q];
#pragma unroll
        for (int tl = 0; tl < 8; tl++) {
            bf16x8 b = W8[(s * 4 + q) * RO + ro0 + tl * 16 + c];
            acc[tl] = __builtin_amdgcn_mfma_f32_16x16x32_bf16(a, b, acc[tl], 0, 0, 0);
        }
    }
    int row_base = n0 + q * 4;
    bool full = (n0 + 15 < N_NODES);
#pragma unroll
    for (int tl = 0; tl < 8; tl++) {
        int col = ro0 + tl * 16 + c;
#pragma unroll
        for (int r = 0; r < 4; r++) {
            int node = row_base + r;
            if (full || node < N_NODES)
                H[(size_t)node * RO + col] = f2bf(acc[tl][r]);
        }
    }
}

// ---------------- aggregate: one wave per node; 4 edges in flight (lane>>4),
// ushort4 channels per lane (lane&15). mode: 0 = f32 out, 1 = relu + bf16 out
__launch_bounds__(256)
__global__ void k_aggregate(const unsigned short* __restrict__ H, const int* __restrict__ rowptr,
                            const int2* __restrict__ edata,
                            const float* __restrict__ bias, float* __restrict__ outf,
                            unsigned short* __restrict__ outb, int mode) {
    int wave = threadIdx.x >> 6;
    int lane = threadIdx.x & 63;
    int node = blockIdx.x * 4 + wave;
    if (node >= N_NODES) return;
    int j0 = rowptr[node];
    int j1 = rowptr[node + 1];
    int es = lane >> 4;          // edge slot 0..3
    int c4 = (lane & 15) * 4;    // channel base
    float a0 = 0.f, a1 = 0.f, a2 = 0.f, a3 = 0.f;
    for (int j = j0 + es; j < j1; j += 4) {
        int2 ed = edata[j];
        int o = ed.x;
        float nn = __int_as_float(ed.y);
        ushort4 v = *(const ushort4*)(H + o + c4);
        a0 += nn * bf2f(v.x);
        a1 += nn * bf2f(v.y);
        a2 += nn * bf2f(v.z);
        a3 += nn * bf2f(v.w);
    }
    a0 += __shfl_xor(a0, 16); a1 += __shfl_xor(a1, 16);
    a2 += __shfl_xor(a2, 16); a3 += __shfl_xor(a3, 16);
    a0 += __shfl_xor(a0, 32); a1 += __shfl_xor(a1, 32);
    a2 += __shfl_xor(a2, 32); a3 += __shfl_xor(a3, 32);
    if (es == 0) {
        float4 b = *(const float4*)(bias + c4);
        float r0 = a0 + b.x, r1 = a1 + b.y, r2 = a2 + b.z, r3 = a3 + b.w;
        if (mode == 1) {
            r0 = fmaxf(r0, 0.f); r1 = fmaxf(r1, 0.f);
            r2 = fmaxf(r2, 0.f); r3 = fmaxf(r3, 0.f);
            ushort4 pk = make_ushort4(f2bf(r0), f2bf(r1), f2bf(r2), f2bf(r3));
            *(ushort4*)&outb[(size_t)node * 64 + c4] = pk;
        } else {
            *(float4*)&outf[(size_t)node * 64 + c4] = make_float4(r0, r1, r2, r3);
        }
    }
}

extern "C" void kernel_launch(void* const* d_in, const int* in_sizes, int n_in,
                              void* d_out, int out_size, void* d_ws, size_t ws_size,
                              hipStream_t stream) {
    const int*   feat  = (const int*)d_in[0];
    const int*   src   = (const int*)d_in[1];
    const int*   dst   = (const int*)d_in[2];
    const int*   etype = (const int*)d_in[3];
    const float* norm  = (const float*)d_in[4];
    const float* emb_w = (const float*)d_in[5];
    const float* sm_w  = (const float*)d_in[6];
    const float* sm_b  = (const float*)d_in[7];
    const float* V1    = (const float*)d_in[8];
    const float* comp1 = (const float*)d_in[9];
    const float* b1    = (const float*)d_in[10];
    const float* V2    = (const float*)d_in[11];
    const float* comp2 = (const float*)d_in[12];
    const float* b2    = (const float*)d_in[13];
    float* out = (float*)d_out;

    char* p = (char*)d_ws;
    auto alloc = [&](size_t bytes) { void* q = (void*)p; p += (bytes + 255) & ~(size_t)255; return q; };
    unsigned short* xb = (unsigned short*)alloc((size_t)N_PAD * 64 * 2);   // 12.8 MB
    unsigned short* hb = (unsigned short*)alloc((size_t)N_PAD * 64 * 2);   // 12.8 MB
    unsigned short* H  = (unsigned short*)alloc((size_t)N_NODES * RO * 2); // 102.4 MB
    unsigned short* Wpack1 = (unsigned short*)alloc(64 * RO * 2);
    unsigned short* Wpack2 = (unsigned short*)alloc(64 * RO * 2);
    unsigned short* smPack = (unsigned short*)alloc(KDIM * HD * 2);        // 32 KB
    int*   deg    = (int*)alloc((size_t)N_NODES * 4);
    int*   ticket = (int*)alloc((size_t)N_EDGES * 4);                      // 6.4 MB
    int*   rowptr = (int*)alloc(((size_t)N_NODES + 1) * 4);
    int*   inc    = (int*)alloc((size_t)N_NODES * 4);
    int*   bsum   = (int*)alloc(512 * 4);
    int*   boff   = (int*)alloc(512 * 4);
    int2*  edata  = (int2*)alloc((size_t)N_EDGES * 8);                     // 12.8 MB

    hipMemsetAsync(deg, 0, (size_t)N_NODES * 4, stream);

    k_weights<<<320, 256, 0, stream>>>(V1, comp1, V2, comp2, sm_w, Wpack1, Wpack2, smPack);
    k_hist<<<N_EDGES / 256, 256, 0, stream>>>(dst, deg, ticket);
    k_scan1<<<NB_SCAN, 256, 0, stream>>>(deg, inc, bsum);
    k_scan2<<<1, 512, 0, stream>>>(bsum, boff);
    k_scan3<<<392, 256, 0, stream>>>(inc, deg, boff, rowptr);
    k_fill<<<N_EDGES / 256, 256, 0, stream>>>(src, dst, etype, norm, rowptr, ticket, edata);

    k_sizematch<<<N_PAD / 64, 256, 0, stream>>>(feat, emb_w, smPack, sm_b, xb);

    k_transform<<<dim3(N_PAD / 64, 4), 256, 0, stream>>>(xb, Wpack1, H);
    k_aggregate<<<N_NODES / 4, 256, 0, stream>>>(H, rowptr, edata, b1, nullptr, hb, 1);

    k_transform<<<dim3(N_PAD / 64, 4), 256, 0, stream>>>(hb, Wpack2, H);
    k_aggregate<<<N_NODES / 4, 256, 0, stream>>>(H, rowptr, edata, b2, out, nullptr, 0);
}